// Round 22
// baseline (1203.895 us; speedup 1.0000x reference)
//
#include <hip/hip_runtime.h>
#include <cstddef>
#include <cstdint>

#define LEAKY(x) ((x) > 0.f ? (x) : 0.2f*(x))

typedef _Float16 f16x8  __attribute__((ext_vector_type(8)));
typedef float    f32x4  __attribute__((ext_vector_type(4)));
typedef float    f32x16 __attribute__((ext_vector_type(16)));

// ws float-offsets
#define WS_FEATS   0            // 32*64*128 = 262144 floats
#define WS_SCORES  262144       // 2048
#define WS_W2      268288       // fp16: 2ck*2pl*9tap*2hf*64co*8 = 36864 halfs (18432 float slots)
#define WS_W1M     287744       // fp16: 2pl*32co*32k = 2048 halfs (1024 float slots)
#define WS_GAPP    288768       // 2048 imgs * 4 quarters * 64 ch = 524288 floats
#define WS_CNT     813056       // 2048 ints (per-image quarter counters)

// ---------------------------------------------------------------------------
// kPack (64 blocks x 256):
//  W2T keyed (ck, pl, tap, hf, co, e): wave lanes (co, hf) read CONTIGUOUS
//  512B segments per (tap,hf) -> fully-coalesced 1KB B-loads (r19's +22%).
//  W1M[plane][co32][k32], k = kh*8 + kw*2 + ci; zero at k%8 in {6,7}, k>=24.
//  Also zeroes the per-image counters (fresh every launch -> graph-safe).
// ---------------------------------------------------------------------------
__global__ void kPack(const float* __restrict__ c1w, const float* __restrict__ c2w,
                      float* __restrict__ ws)
{
    _Float16* W2 = (_Float16*)(ws + WS_W2);
    _Float16* W1 = (_Float16*)(ws + WS_W1M);
    int* cnt = (int*)(ws + WS_CNT);
    const int t = blockIdx.x*256 + threadIdx.x;
    for (int i = t; i < 2*2*9*2*64*8; i += 64*256) {
        int idx = i;
        const int e   = idx & 7;  idx >>= 3;
        const int co  = idx & 63; idx >>= 6;
        const int hf  = idx & 1;  idx >>= 1;
        const int tap = idx % 9;  idx /= 9;
        const int pl  = idx & 1;
        const int ck  = idx >> 1;
        const int cil = hf*8 + e;
        float wv = c2w[(co*32 + ck*16 + cil)*9 + tap];
        _Float16 h = (_Float16)wv;
        W2[i] = pl ? (_Float16)(wv - (float)h) : h;
    }
    if (t < 2048) {
        cnt[t] = 0;
        int pl = t >> 10, rest = t & 1023;
        int co = rest >> 5, k = rest & 31;
        int kh = k >> 3, j = k & 7, kw = j >> 1, ci = j & 1;
        float wv = 0.f;
        if (kh < 3 && kw < 3) wv = c1w[co*18 + ci*9 + kh*3 + kw];
        _Float16 hi = (_Float16)wv;
        W1[t] = pl ? (_Float16)(wv - (float)hi) : hi;
    }
}

// x1 LDS addressing (halfs) within one chunk buffer (padded strides).
__device__ __forceinline__ int x1_off(int pl, int hf, int row, int xp, int xq) {
    return (pl*2 + hf)*2528 + row*280 + (xp*17 + xq)*8;
}
#define X1_HALFS (2*2*2528)   // per chunk: 10112 halfs = 20224 B

// ---------------------------------------------------------------------------
// kConv: QUARTER image per block. bid = n*4 + q (8192 blocks x 512 thr,
// 8 waves). K-split: wave w = {ck = w>>2, mt, nh}; conv1+conv2 for chunk ck
// (27 conv2 MFMAs); chunk-1 waves ship acc via LDS; chunk-0 combine+GAP.
// Coalesced W2T B-loads (r19) + targeted pad zeroing (r20). NEW this round:
//  (a) conv2 A-addresses = ONE base pointer + compile-time tap offsets
//      (kh*280 + {0,136,8}[kw]) -> 18 ds_read_b128 with immediate offsets,
//      ~90 addr-VALU/wave removed.
//  (b) fused scorer: per-image atomic counter; the LAST of an image's 4
//      quarter-blocks runs the proj+MLP epilogue (fence/acquire; fixed
//      gapp read order -> deterministic). kScore kernel eliminated.
// Do NOT re-attempt: x1 dbuf (r13), manual B-prefetch (r14), bank pads
// (r16), launch_bounds budget (r17), tail batching below device width (r20).
// LDS = 50,784 B. Bare bounds.
// ---------------------------------------------------------------------------
__global__ __launch_bounds__(512) void kConv(
    const float* __restrict__ texts, const float* __restrict__ styles,
    const float* __restrict__ c1b, const float* __restrict__ c2b,
    const float* __restrict__ pw,  const float* __restrict__ pb,
    const float* __restrict__ v1w, const float* __restrict__ v1b,
    const float* __restrict__ v2w, const float* __restrict__ v2b,
    const float* __restrict__ v3w, const float* __restrict__ v3b,
    const float* __restrict__ wsro,
    float* __restrict__ gapp, float* __restrict__ feats,
    float* __restrict__ scores, int* __restrict__ cnt)
{
    __shared__ __align__(16) union {
        _Float16 in[2][19][68][2];                          // 10,336 B
        float    part[4][32];                               // (aliased, used last)
    } s_u;
    __shared__ __align__(16) _Float16 s_x1[2][X1_HALFS];    // 40,448 B (2 chunks)
    __shared__ int s_last;

    const int bid = blockIdx.x, tid = threadIdx.x;
    const int n = bid >> 2, q = bid & 3;
    const int w = tid >> 6, l = tid & 63;

    // ---- TARGETED pad zeroing ----
    {
        const uint4 z4 = {0u,0u,0u,0u};
        if (tid < 72) {           // col-32 pad: (ck,pl,hf,row 0..8, xp0,xq16)
            int i = tid;
            const int ck = i >= 36; i -= ck*36;
            const int pl = i >= 18; i -= pl*18;
            const int hf = i >= 9;  const int row = i - hf*9;
            *(uint4*)&s_x1[ck][x1_off(pl, hf, row, 0, 16)] = z4;
        }
        if (q == 3 && tid >= 128 && tid < 400) {  // row-8 pad (conv1 skips it)
            const int i = tid - 128;              // 0..271 = 8 grp x 34 slots
            const int grp = i / 34, s = i - grp*34;
            const int ck = grp >> 2, pl = (grp >> 1) & 1, hf = grp & 1;
            *(uint4*)&s_x1[ck][(pl*2 + hf)*2528 + 8*280 + s*8] = z4;
        }
        if (tid < 38) {           // s_in pad cols x=64..67, both planes
            int pl = tid >= 19, row = pl ? tid - 19 : tid;
            *(uint4*)&s_u.in[pl][row][64][0] = z4;
        }
    }
    // stage input rows 16q..16q+18, fp16 hi/lo interleaved (rows>=64 zero)
    for (int u = tid; u < 304; u += 512) {
        const int row = u >> 4, g = u & 15;
        const int grow = q*16 + row;
        float4 tv = {0.f,0.f,0.f,0.f}, sv = {0.f,0.f,0.f,0.f};
        if (grow < 64) {
            tv = *(const float4*)&texts [(size_t)n*4096 + grow*64 + g*4];
            sv = *(const float4*)&styles[(size_t)n*4096 + grow*64 + g*4];
        }
        float vals[8] = {tv.x, sv.x, tv.y, sv.y, tv.z, sv.z, tv.w, sv.w};
        _Float16 hh[8], ll[8];
        #pragma unroll
        for (int j = 0; j < 8; ++j) {
            _Float16 hi = (_Float16)vals[j];
            hh[j] = hi; ll[j] = (_Float16)(vals[j] - (float)hi);
        }
        *(uint4*)&s_u.in[0][row][g*4][0] = *(uint4*)hh;
        *(uint4*)&s_u.in[1][row][g*4][0] = *(uint4*)ll;
    }
    __syncthreads();

    const _Float16* W2h = (const _Float16*)(wsro + WS_W2);
    const _Float16* W1g = (const _Float16*)(wsro + WS_W1M);

    f32x16 acc;
    #pragma unroll
    for (int r = 0; r < 16; ++r) acc[r] = 0.f;

    // wave roles: ck = chunk, (mt, nh) = output tile
    const int ck = w >> 2, sw = w & 3;
    const int mt = (w >> 1) & 1, nh = w & 1;
    const int posl = mt*32 + (l & 31);
    const int py2 = posl >> 4, px2 = posl & 15;
    const int hf2 = l >> 5;
    const int co2 = nh*32 + (l & 31);
    // conv1 lane roles
    const int kg = l >> 4, m16 = l & 15;
    const int NT = (q == 3) ? 16 : 18;   // q=3 skips py=8 (x1 row 8 = zero pad)

    // ---- conv1 via MFMA: chunk ck, tiles sw, sw+4, ... ----
    {
        f16x8 a_h = *(const f16x8*)&W1g[(0*32 + ck*16 + m16)*32 + kg*8];
        f16x8 a_l = *(const f16x8*)&W1g[(1*32 + ck*16 + m16)*32 + kg*8];
        float4 b4 = *(const float4*)&c1b[ck*16 + kg*4];
        for (int t = sw; t < NT; t += 4) {
            const int py = t >> 1, px = (t & 1)*16 + m16;
            const int row = (kg < 3) ? (2*py + kg) : (2*py);  // kg=3: dead, alias
            const _Float16* bp0 = &s_u.in[0][row][2*px][0];
            const _Float16* bp1 = &s_u.in[1][row][2*px][0];
            f16x8 b_h, b_l;
            ((uint2*)&b_h)[0] = *(const uint2*)bp0;
            ((uint2*)&b_h)[1] = *(const uint2*)(bp0 + 4);
            ((uint2*)&b_l)[0] = *(const uint2*)bp1;
            ((uint2*)&b_l)[1] = *(const uint2*)(bp1 + 4);
            f32x4 c = {0.f,0.f,0.f,0.f};
            c = __builtin_amdgcn_mfma_f32_16x16x32_f16(a_l, b_h, c, 0, 0, 0);
            c = __builtin_amdgcn_mfma_f32_16x16x32_f16(a_h, b_l, c, 0, 0, 0);
            c = __builtin_amdgcn_mfma_f32_16x16x32_f16(a_h, b_h, c, 0, 0, 0);
            // C: col=l&15=pos, row=kg*4+reg=co -> 4 consecutive ci
            const int xp = px & 1, xq = px >> 1;
            _Float16 hh[4], ll[4];
            #pragma unroll
            for (int r = 0; r < 4; ++r) {
                float v = c[r] + b4[r];
                v = fmaxf(v, 0.2f*v);          // leaky
                _Float16 hi = (_Float16)v;
                hh[r] = hi; ll[r] = (_Float16)(v - (float)hi);
            }
            const int eo = (kg & 1)*4;
            *(uint2*)&s_x1[ck][x1_off(0, kg >> 1, py, xp, xq) + eo] = *(uint2*)hh;
            *(uint2*)&s_x1[ck][x1_off(1, kg >> 1, py, xp, xq) + eo] = *(uint2*)ll;
        }
    }
    __syncthreads();   // both chunks' x1 ready

    // ---- conv2: chunk ck, single pass, 27 MFMA; A = base + const offsets ----
    {
        const _Float16* Bg_h = W2h + (size_t)(ck*2 + 0)*9216 + hf2*512 + co2*8;
        const _Float16* Bg_l = Bg_h + 9216;
        // A base: pl=0 plane of this (hf2, row=2*py2, col px2); pl=1 = +5056
        const _Float16* a_base = &s_x1[ck][hf2*2528 + (2*py2)*280 + px2*8];
        #pragma unroll
        for (int tap = 0; tap < 9; ++tap) {
            const int kh = tap/3, kw = tap%3;
            const int aofs = kh*280 + (kw == 0 ? 0 : (kw == 1 ? 136 : 8));
            f16x8 Ah = *(const f16x8*)(a_base + aofs);
            f16x8 Al = *(const f16x8*)(a_base + 5056 + aofs);
            f16x8 Bh = *(const f16x8*)&Bg_h[tap*1024];
            f16x8 Bl = *(const f16x8*)&Bg_l[tap*1024];
            acc = __builtin_amdgcn_mfma_f32_32x32x16_f16(Ah, Bh, acc, 0, 0, 0);
            acc = __builtin_amdgcn_mfma_f32_32x32x16_f16(Al, Bh, acc, 0, 0, 0);
            acc = __builtin_amdgcn_mfma_f32_32x32x16_f16(Ah, Bl, acc, 0, 0, 0);
        }
    }
    __syncthreads();   // all conv2 done; x1 dead -> reuse as acc-combine buf

    // ---- combine chunk partial accs: wave w+4 -> wave w ----
    float* comb = (float*)&s_x1[0][0];     // 4 waves * 64 lanes * 18 f
    if (ck == 1) {
        float* dst = comb + ((w - 4)*64 + l)*18;
        #pragma unroll
        for (int r = 0; r < 16; r += 2)
            *(float2*)&dst[r] = make_float2(acc[r], acc[r+1]);
    }
    __syncthreads();
    if (ck == 0) {
        const float* src = comb + (w*64 + l)*18;
        const float b2 = c2b[co2];
        float s = 0.f;
        #pragma unroll
        for (int r = 0; r < 16; ++r) {
            float v = acc[r] + src[r] + b2;
            s += fmaxf(v, 0.2f*v);
        }
        s += __shfl_xor(s, 32);
        if (l < 32) s_u.part[w][l] = s;    // s_in dead (barriers in between)
    }
    __syncthreads();
    if (tid < 64) {
        const int nhc = tid >> 5, cl = tid & 31;
        float g = s_u.part[0*2 + nhc][cl] + s_u.part[1*2 + nhc][cl];
        gapp[(size_t)(n*4 + q)*64 + tid] = g;
        __threadfence();                   // make gapp visible device-wide
    }
    __syncthreads();
    if (tid == 0) s_last = (atomicAdd(&cnt[n], 1) == 3);
    __syncthreads();

    // ---- fused scorer: only the LAST quarter-block of image n runs this.
    //      Deterministic: fixed gapp read order, executor-independent. ----
    if (s_last) {
        __threadfence();                   // acquire: see all quarters' gapp
        float* sc = (float*)&s_x1[0][0];   // reuse dead x1: gap|f|h|red
        float* s_gap = sc, *s_f = sc + 64, *s_h = sc + 192, *s_red = sc + 320;
        if (tid < 64) {
            const float* gp = &gapp[(size_t)n*256 + tid];
            s_gap[tid] = (gp[0] + gp[64] + gp[128] + gp[192]) * (1.f/256.f);
        }
        __syncthreads();
        if (tid < 128) {
            float a = pb[tid];
            #pragma unroll 8
            for (int m = 0; m < 64; ++m) a += s_gap[m]*pw[m*128 + tid];
            feats[(size_t)n*128 + tid] = a;
            s_f[tid] = a;
        }
        __syncthreads();
        if (tid < 128) {
            float a = v1b[tid];
            #pragma unroll 8
            for (int m = 0; m < 128; ++m) a += s_f[m]*v1w[m*128 + tid];
            s_h[tid] = LEAKY(a);
        }
        __syncthreads();
        if (tid < 128) {
            float a = v2b[tid];
            #pragma unroll 8
            for (int m = 0; m < 128; ++m) a += s_h[m]*v2w[m*128 + tid];
            a = LEAKY(a);
            s_f[tid] = a * v3w[tid];
        }
        __syncthreads();
        if (tid < 128) {
            float p = s_f[tid];
            #pragma unroll
            for (int off = 32; off; off >>= 1) p += __shfl_xor(p, off);
            if ((tid & 63) == 0) s_red[tid >> 6] = p;
        }
        __syncthreads();
        if (tid == 0) scores[n] = tanhf(s_red[0] + s_red[1] + v3b[0]);
    }
}

// ---------------------------------------------------------------------------
// kDecode: argmax (first-index tie-break, recomputed per block) + gather
// + decoder (fp32) — 256 blocks x 512. bid%8 -> same d2 column slice / XCD.
// ---------------------------------------------------------------------------
__global__ __launch_bounds__(512) void kDecode(
    const float* __restrict__ scores, const float* __restrict__ feats,
    const float* __restrict__ d1w, const float* __restrict__ d1b,
    const float* __restrict__ d2w, const float* __restrict__ d2b,
    float* __restrict__ out)
{
    __shared__ float s_res[128];
    __shared__ float s_h[512];
    __shared__ int s_idx;
    const int bid = blockIdx.x;
    const int b = bid >> 3, ot = bid & 7;
    const int tid = threadIdx.x;

    if (tid < 64) {
        float v = scores[b*64 + tid];
        int   i = tid;
        #pragma unroll
        for (int off = 32; off; off >>= 1) {
            float ov = __shfl_xor(v, off);
            int   oi = __shfl_xor(i, off);
            if (ov > v || (ov == v && oi < i)) { v = ov; i = oi; }
        }
        if (tid == 0) s_idx = i;
    }
    __syncthreads();
    if (tid < 128) s_res[tid] = feats[((size_t)b*64 + s_idx)*128 + tid];
    __syncthreads();
    {
        float a = d1b[tid];
        #pragma unroll 8
        for (int m = 0; m < 128; ++m) a += s_res[m]*d1w[m*512 + tid];
        s_h[tid] = LEAKY(a);
    }
    __syncthreads();
    const int o = ot*512 + tid;
    float a = d2b[o];
    for (int k = 0; k < 512; k += 4) {
        float4 h4 = *(const float4*)&s_h[k];
        a += h4.x*d2w[(size_t)(k+0)*4096 + o];
        a += h4.y*d2w[(size_t)(k+1)*4096 + o];
        a += h4.z*d2w[(size_t)(k+2)*4096 + o];
        a += h4.w*d2w[(size_t)(k+3)*4096 + o];
    }
    out[(size_t)b*4096 + o] = tanhf(a);
}

// ---------------------------------------------------------------------------
extern "C" void kernel_launch(void* const* d_in, const int* in_sizes, int n_in,
                              void* d_out, int out_size, void* d_ws, size_t ws_size,
                              hipStream_t stream)
{
    const float* texts  = (const float*)d_in[0];
    const float* styles = (const float*)d_in[1];
    const float* c1w = (const float*)d_in[2];
    const float* c1b = (const float*)d_in[3];
    const float* c2w = (const float*)d_in[4];
    const float* c2b = (const float*)d_in[5];
    const float* pw  = (const float*)d_in[6];
    const float* pb  = (const float*)d_in[7];
    const float* v1w = (const float*)d_in[8];
    const float* v1b = (const float*)d_in[9];
    const float* v2w = (const float*)d_in[10];
    const float* v2b = (const float*)d_in[11];
    const float* v3w = (const float*)d_in[12];
    const float* v3b = (const float*)d_in[13];
    const float* d1w = (const float*)d_in[14];
    const float* d1b = (const float*)d_in[15];
    const float* d2w = (const float*)d_in[16];
    const float* d2b = (const float*)d_in[17];

    float* ws     = (float*)d_ws;
    float* feats  = ws + WS_FEATS;
    float* scores = ws + WS_SCORES;
    float* gapp   = ws + WS_GAPP;
    int*   cnt    = (int*)(ws + WS_CNT);

    kPack<<<dim3(64), dim3(256), 0, stream>>>(c1w, c2w, ws);
    kConv<<<dim3(8192), dim3(512), 0, stream>>>(
        texts, styles, c1b, c2b, pw, pb, v1w, v1b, v2w, v2b, v3w, v3b,
        (const float*)ws, gapp, feats, scores, cnt);
    kDecode<<<dim3(256), dim3(512), 0, stream>>>(
        scores, feats, d1w, d1b, d2w, d2b, (float*)d_out);
}

// Round 23
// 123.293 us; speedup vs baseline: 9.7645x; 9.7645x over previous
//
#include <hip/hip_runtime.h>
#include <cstddef>
#include <cstdint>

#define LEAKY(x) ((x) > 0.f ? (x) : 0.2f*(x))

typedef _Float16 f16x8  __attribute__((ext_vector_type(8)));
typedef float    f32x4  __attribute__((ext_vector_type(4)));
typedef float    f32x16 __attribute__((ext_vector_type(16)));

// ws float-offsets
#define WS_FEATS   0            // 32*64*128 = 262144 floats
#define WS_SCORES  262144       // 2048
#define WS_W2      268288       // fp16: 2ck*2pl*9tap*2hf*64co*8 = 36864 halfs (18432 float slots)
#define WS_W1M     287744       // fp16: 2pl*32co*32k = 2048 halfs (1024 float slots)
#define WS_GAPP    288768       // 2048 imgs * 4 quarters * 64 ch = 524288 floats

// ---------------------------------------------------------------------------
// kPack (64 blocks x 256):
//  W2T keyed (ck, pl, tap, hf, co, e): wave lanes (co, hf) read CONTIGUOUS
//  512B segments per (tap,hf) -> fully-coalesced 1KB B-loads (r19's +22%).
//  W1M[plane][co32][k32], k = kh*8 + kw*2 + ci; zero at k%8 in {6,7}, k>=24.
// ---------------------------------------------------------------------------
__global__ void kPack(const float* __restrict__ c1w, const float* __restrict__ c2w,
                      float* __restrict__ ws)
{
    _Float16* W2 = (_Float16*)(ws + WS_W2);
    _Float16* W1 = (_Float16*)(ws + WS_W1M);
    const int t = blockIdx.x*256 + threadIdx.x;
    for (int i = t; i < 2*2*9*2*64*8; i += 64*256) {
        int idx = i;
        const int e   = idx & 7;  idx >>= 3;
        const int co  = idx & 63; idx >>= 6;
        const int hf  = idx & 1;  idx >>= 1;
        const int tap = idx % 9;  idx /= 9;
        const int pl  = idx & 1;
        const int ck  = idx >> 1;
        const int cil = hf*8 + e;
        float wv = c2w[(co*32 + ck*16 + cil)*9 + tap];
        _Float16 h = (_Float16)wv;
        W2[i] = pl ? (_Float16)(wv - (float)h) : h;
    }
    if (t < 2048) {
        int pl = t >> 10, rest = t & 1023;
        int co = rest >> 5, k = rest & 31;
        int kh = k >> 3, j = k & 7, kw = j >> 1, ci = j & 1;
        float wv = 0.f;
        if (kh < 3 && kw < 3) wv = c1w[co*18 + ci*9 + kh*3 + kw];
        _Float16 hi = (_Float16)wv;
        W1[t] = pl ? (_Float16)(wv - (float)hi) : hi;
    }
}

// x1 LDS addressing (halfs) within one chunk buffer (padded strides).
__device__ __forceinline__ int x1_off(int pl, int hf, int row, int xp, int xq) {
    return (pl*2 + hf)*2528 + row*280 + (xp*17 + xq)*8;
}
#define X1_HALFS (2*2*2528)   // per chunk: 10112 halfs = 20224 B

// ---------------------------------------------------------------------------
// kConv: QUARTER image per block. bid = n*4 + q (8192 blocks x 512 thr,
// 8 waves). K-split: wave w = {ck = w>>2, mt, nh}; conv1+conv2 for chunk ck
// (27 conv2 MFMAs); chunk-1 waves ship acc via LDS; chunk-0 combine+GAP.
// Coalesced W2T B-loads (r19) + targeted pad zeroing (r20) + conv2
// A-addresses as base + compile-time tap offsets (r22a: saves ~90
// addr-VALU/wave, sync-free).
// Do NOT re-attempt: x1 dbuf (r13), manual B-prefetch (r14), bank pads
// (r16), launch_bounds budget (r17), tail batching below device width
// (r20), and FUSED SCORER VIA ATOMIC+THREADFENCE (r22: device-scope fences
// from 8192 blocks storm the non-coherent per-XCD L2s -> 10x regression).
// LDS = 50,784 B. Bare bounds.
// ---------------------------------------------------------------------------
__global__ __launch_bounds__(512) void kConv(
    const float* __restrict__ texts, const float* __restrict__ styles,
    const float* __restrict__ c1b, const float* __restrict__ c2b,
    const float* __restrict__ wsro, float* __restrict__ gapp)
{
    __shared__ __align__(16) union {
        _Float16 in[2][19][68][2];                          // 10,336 B
        float    part[4][32];                               // (aliased, used last)
    } s_u;
    __shared__ __align__(16) _Float16 s_x1[2][X1_HALFS];    // 40,448 B (2 chunks)

    const int bid = blockIdx.x, tid = threadIdx.x;
    const int n = bid >> 2, q = bid & 3;
    const int w = tid >> 6, l = tid & 63;

    // ---- TARGETED pad zeroing ----
    {
        const uint4 z4 = {0u,0u,0u,0u};
        if (tid < 72) {           // col-32 pad: (ck,pl,hf,row 0..8, xp0,xq16)
            int i = tid;
            const int ck = i >= 36; i -= ck*36;
            const int pl = i >= 18; i -= pl*18;
            const int hf = i >= 9;  const int row = i - hf*9;
            *(uint4*)&s_x1[ck][x1_off(pl, hf, row, 0, 16)] = z4;
        }
        if (q == 3 && tid >= 128 && tid < 400) {  // row-8 pad (conv1 skips it)
            const int i = tid - 128;              // 0..271 = 8 grp x 34 slots
            const int grp = i / 34, s = i - grp*34;
            const int ck = grp >> 2, pl = (grp >> 1) & 1, hf = grp & 1;
            *(uint4*)&s_x1[ck][(pl*2 + hf)*2528 + 8*280 + s*8] = z4;
        }
        if (tid < 38) {           // s_in pad cols x=64..67, both planes
            int pl = tid >= 19, row = pl ? tid - 19 : tid;
            *(uint4*)&s_u.in[pl][row][64][0] = z4;
        }
    }
    // stage input rows 16q..16q+18, fp16 hi/lo interleaved (rows>=64 zero)
    for (int u = tid; u < 304; u += 512) {
        const int row = u >> 4, g = u & 15;
        const int grow = q*16 + row;
        float4 tv = {0.f,0.f,0.f,0.f}, sv = {0.f,0.f,0.f,0.f};
        if (grow < 64) {
            tv = *(const float4*)&texts [(size_t)n*4096 + grow*64 + g*4];
            sv = *(const float4*)&styles[(size_t)n*4096 + grow*64 + g*4];
        }
        float vals[8] = {tv.x, sv.x, tv.y, sv.y, tv.z, sv.z, tv.w, sv.w};
        _Float16 hh[8], ll[8];
        #pragma unroll
        for (int j = 0; j < 8; ++j) {
            _Float16 hi = (_Float16)vals[j];
            hh[j] = hi; ll[j] = (_Float16)(vals[j] - (float)hi);
        }
        *(uint4*)&s_u.in[0][row][g*4][0] = *(uint4*)hh;
        *(uint4*)&s_u.in[1][row][g*4][0] = *(uint4*)ll;
    }
    __syncthreads();

    const _Float16* W2h = (const _Float16*)(wsro + WS_W2);
    const _Float16* W1g = (const _Float16*)(wsro + WS_W1M);

    f32x16 acc;
    #pragma unroll
    for (int r = 0; r < 16; ++r) acc[r] = 0.f;

    // wave roles: ck = chunk, (mt, nh) = output tile
    const int ck = w >> 2, sw = w & 3;
    const int mt = (w >> 1) & 1, nh = w & 1;
    const int posl = mt*32 + (l & 31);
    const int py2 = posl >> 4, px2 = posl & 15;
    const int hf2 = l >> 5;
    const int co2 = nh*32 + (l & 31);
    // conv1 lane roles
    const int kg = l >> 4, m16 = l & 15;
    const int NT = (q == 3) ? 16 : 18;   // q=3 skips py=8 (x1 row 8 = zero pad)

    // ---- conv1 via MFMA: chunk ck, tiles sw, sw+4, ... ----
    {
        f16x8 a_h = *(const f16x8*)&W1g[(0*32 + ck*16 + m16)*32 + kg*8];
        f16x8 a_l = *(const f16x8*)&W1g[(1*32 + ck*16 + m16)*32 + kg*8];
        float4 b4 = *(const float4*)&c1b[ck*16 + kg*4];
        for (int t = sw; t < NT; t += 4) {
            const int py = t >> 1, px = (t & 1)*16 + m16;
            const int row = (kg < 3) ? (2*py + kg) : (2*py);  // kg=3: dead, alias
            const _Float16* bp0 = &s_u.in[0][row][2*px][0];
            const _Float16* bp1 = &s_u.in[1][row][2*px][0];
            f16x8 b_h, b_l;
            ((uint2*)&b_h)[0] = *(const uint2*)bp0;
            ((uint2*)&b_h)[1] = *(const uint2*)(bp0 + 4);
            ((uint2*)&b_l)[0] = *(const uint2*)bp1;
            ((uint2*)&b_l)[1] = *(const uint2*)(bp1 + 4);
            f32x4 c = {0.f,0.f,0.f,0.f};
            c = __builtin_amdgcn_mfma_f32_16x16x32_f16(a_l, b_h, c, 0, 0, 0);
            c = __builtin_amdgcn_mfma_f32_16x16x32_f16(a_h, b_l, c, 0, 0, 0);
            c = __builtin_amdgcn_mfma_f32_16x16x32_f16(a_h, b_h, c, 0, 0, 0);
            // C: col=l&15=pos, row=kg*4+reg=co -> 4 consecutive ci
            const int xp = px & 1, xq = px >> 1;
            _Float16 hh[4], ll[4];
            #pragma unroll
            for (int r = 0; r < 4; ++r) {
                float v = c[r] + b4[r];
                v = fmaxf(v, 0.2f*v);          // leaky
                _Float16 hi = (_Float16)v;
                hh[r] = hi; ll[r] = (_Float16)(v - (float)hi);
            }
            const int eo = (kg & 1)*4;
            *(uint2*)&s_x1[ck][x1_off(0, kg >> 1, py, xp, xq) + eo] = *(uint2*)hh;
            *(uint2*)&s_x1[ck][x1_off(1, kg >> 1, py, xp, xq) + eo] = *(uint2*)ll;
        }
    }
    __syncthreads();   // both chunks' x1 ready

    // ---- conv2: chunk ck, single pass, 27 MFMA; A = base + const offsets ----
    {
        const _Float16* Bg_h = W2h + (size_t)(ck*2 + 0)*9216 + hf2*512 + co2*8;
        const _Float16* Bg_l = Bg_h + 9216;
        // A base: pl=0 plane of (hf2, row=2*py2, col px2); pl=1 = +5056.
        // Tap offset: kh*280 + {kw0:0, kw1:(17*8)=136, kw2:8} (xp,xq fold).
        const _Float16* a_base = &s_x1[ck][hf2*2528 + (2*py2)*280 + px2*8];
        #pragma unroll
        for (int tap = 0; tap < 9; ++tap) {
            const int kh = tap/3, kw = tap%3;
            const int aofs = kh*280 + (kw == 0 ? 0 : (kw == 1 ? 136 : 8));
            f16x8 Ah = *(const f16x8*)(a_base + aofs);
            f16x8 Al = *(const f16x8*)(a_base + 5056 + aofs);
            f16x8 Bh = *(const f16x8*)&Bg_h[tap*1024];
            f16x8 Bl = *(const f16x8*)&Bg_l[tap*1024];
            acc = __builtin_amdgcn_mfma_f32_32x32x16_f16(Ah, Bh, acc, 0, 0, 0);
            acc = __builtin_amdgcn_mfma_f32_32x32x16_f16(Al, Bh, acc, 0, 0, 0);
            acc = __builtin_amdgcn_mfma_f32_32x32x16_f16(Ah, Bl, acc, 0, 0, 0);
        }
    }
    __syncthreads();   // all conv2 done; x1 dead -> reuse as acc-combine buf

    // ---- combine chunk partial accs: wave w+4 -> wave w ----
    float* comb = (float*)&s_x1[0][0];     // 4 waves * 64 lanes * 18 f
    if (ck == 1) {
        float* dst = comb + ((w - 4)*64 + l)*18;
        #pragma unroll
        for (int r = 0; r < 16; r += 2)
            *(float2*)&dst[r] = make_float2(acc[r], acc[r+1]);
    }
    __syncthreads();
    if (ck == 0) {
        const float* src = comb + (w*64 + l)*18;
        const float b2 = c2b[co2];
        float s = 0.f;
        #pragma unroll
        for (int r = 0; r < 16; ++r) {
            float v = acc[r] + src[r] + b2;
            s += fmaxf(v, 0.2f*v);
        }
        s += __shfl_xor(s, 32);
        if (l < 32) s_u.part[w][l] = s;    // s_in dead (barriers in between)
    }
    __syncthreads();
    if (tid < 64) {
        const int nhc = tid >> 5, cl = tid & 31;
        float g = s_u.part[0*2 + nhc][cl] + s_u.part[1*2 + nhc][cl];
        gapp[(size_t)(n*4 + q)*64 + tid] = g;
    }
}

// ---------------------------------------------------------------------------
// kScore: per image (2048 blocks x 128 thr) — r19/r21 version. Grid width
// over traffic (r20 lesson); separate kernel, no cross-block sync (r22
// lesson: atomic+threadfence fusion storms the non-coherent L2s).
// ---------------------------------------------------------------------------
__global__ __launch_bounds__(128) void kScore(
    const float* __restrict__ gapp,
    const float* __restrict__ pw,  const float* __restrict__ pb,
    const float* __restrict__ v1w, const float* __restrict__ v1b,
    const float* __restrict__ v2w, const float* __restrict__ v2b,
    const float* __restrict__ v3w, const float* __restrict__ v3b,
    float* __restrict__ feats, float* __restrict__ scores)
{
    __shared__ float s_gap[64], s_f[128], s_h[128], s_red[2];
    const int n = blockIdx.x, tid = threadIdx.x;

    if (tid < 64) {
        const float* gp = &gapp[(size_t)n*256 + tid];
        s_gap[tid] = (gp[0] + gp[64] + gp[128] + gp[192]) * (1.f/256.f);
    }
    __syncthreads();
    {
        float a = pb[tid];
        #pragma unroll 8
        for (int m = 0; m < 64; ++m) a += s_gap[m]*pw[m*128 + tid];
        feats[(size_t)n*128 + tid] = a;
        s_f[tid] = a;
    }
    __syncthreads();
    {
        float a = v1b[tid];
        #pragma unroll 8
        for (int m = 0; m < 128; ++m) a += s_f[m]*v1w[m*128 + tid];
        s_h[tid] = LEAKY(a);
    }
    __syncthreads();
    {
        float a = v2b[tid];
        #pragma unroll 8
        for (int m = 0; m < 128; ++m) a += s_h[m]*v2w[m*128 + tid];
        a = LEAKY(a);
        s_f[tid] = a * v3w[tid];
    }
    __syncthreads();
    {
        float p = s_f[tid];
        #pragma unroll
        for (int off = 32; off; off >>= 1) p += __shfl_xor(p, off);
        if ((tid & 63) == 0) s_red[tid >> 6] = p;
    }
    __syncthreads();
    if (tid == 0) scores[n] = tanhf(s_red[0] + s_red[1] + v3b[0]);
}

// ---------------------------------------------------------------------------
// kDecode: argmax (first-index tie-break, recomputed per block) + gather
// + decoder (fp32) — 256 blocks x 512. bid%8 -> same d2 column slice / XCD.
// ---------------------------------------------------------------------------
__global__ __launch_bounds__(512) void kDecode(
    const float* __restrict__ scores, const float* __restrict__ feats,
    const float* __restrict__ d1w, const float* __restrict__ d1b,
    const float* __restrict__ d2w, const float* __restrict__ d2b,
    float* __restrict__ out)
{
    __shared__ float s_res[128];
    __shared__ float s_h[512];
    __shared__ int s_idx;
    const int bid = blockIdx.x;
    const int b = bid >> 3, ot = bid & 7;
    const int tid = threadIdx.x;

    if (tid < 64) {
        float v = scores[b*64 + tid];
        int   i = tid;
        #pragma unroll
        for (int off = 32; off; off >>= 1) {
            float ov = __shfl_xor(v, off);
            int   oi = __shfl_xor(i, off);
            if (ov > v || (ov == v && oi < i)) { v = ov; i = oi; }
        }
        if (tid == 0) s_idx = i;
    }
    __syncthreads();
    if (tid < 128) s_res[tid] = feats[((size_t)b*64 + s_idx)*128 + tid];
    __syncthreads();
    {
        float a = d1b[tid];
        #pragma unroll 8
        for (int m = 0; m < 128; ++m) a += s_res[m]*d1w[m*512 + tid];
        s_h[tid] = LEAKY(a);
    }
    __syncthreads();
    const int o = ot*512 + tid;
    float a = d2b[o];
    for (int k = 0; k < 512; k += 4) {
        float4 h4 = *(const float4*)&s_h[k];
        a += h4.x*d2w[(size_t)(k+0)*4096 + o];
        a += h4.y*d2w[(size_t)(k+1)*4096 + o];
        a += h4.z*d2w[(size_t)(k+2)*4096 + o];
        a += h4.w*d2w[(size_t)(k+3)*4096 + o];
    }
    out[(size_t)b*4096 + o] = tanhf(a);
}

// ---------------------------------------------------------------------------
extern "C" void kernel_launch(void* const* d_in, const int* in_sizes, int n_in,
                              void* d_out, int out_size, void* d_ws, size_t ws_size,
                              hipStream_t stream)
{
    const float* texts  = (const float*)d_in[0];
    const float* styles = (const float*)d_in[1];
    const float* c1w = (const float*)d_in[2];
    const float* c1b = (const float*)d_in[3];
    const float* c2w = (const float*)d_in[4];
    const float* c2b = (const float*)d_in[5];
    const float* pw  = (const float*)d_in[6];
    const float* pb  = (const float*)d_in[7];
    const float* v1w = (const float*)d_in[8];
    const float* v1b = (const float*)d_in[9];
    const float* v2w = (const float*)d_in[10];
    const float* v2b = (const float*)d_in[11];
    const float* v3w = (const float*)d_in[12];
    const float* v3b = (const float*)d_in[13];
    const float* d1w = (const float*)d_in[14];
    const float* d1b = (const float*)d_in[15];
    const float* d2w = (const float*)d_in[16];
    const float* d2b = (const float*)d_in[17];

    float* ws     = (float*)d_ws;
    float* feats  = ws + WS_FEATS;
    float* scores = ws + WS_SCORES;
    float* gapp   = ws + WS_GAPP;

    kPack<<<dim3(64), dim3(256), 0, stream>>>(c1w, c2w, ws);
    kConv<<<dim3(8192), dim3(512), 0, stream>>>(
        texts, styles, c1b, c2b, (const float*)ws, gapp);
    kScore<<<dim3(2048), dim3(128), 0, stream>>>(
        gapp, pw, pb, v1w, v1b, v2w, v2b, v3w, v3b, feats, scores);
    kDecode<<<dim3(256), dim3(512), 0, stream>>>(
        scores, feats, d1w, d1b, d2w, d2b, (float*)d_out);
}